// Round 1
// baseline (353.742 us; speedup 1.0000x reference)
//
#include <hip/hip_runtime.h>
#include <hip/hip_bf16.h>
#include <math.h>

#define S_LEN 4096
#define DMODEL 2048
#define HEADD 128

typedef __attribute__((ext_vector_type(8))) short short8;
typedef __attribute__((ext_vector_type(4))) float floatx4;

__device__ __forceinline__ short f2bs(float f) {
  __hip_bfloat16 h = __float2bfloat16(f);
  short s; __builtin_memcpy(&s, &h, 2); return s;
}

// ---- Kernel 1: convert Wq,Wk,Wv (fp32 [128][2048] each) -> wc bf16 [384][2048]
__global__ __launch_bounds__(256) void convw_kernel(const float* __restrict__ wq,
                                                    const float* __restrict__ wk,
                                                    const float* __restrict__ wv,
                                                    short* __restrict__ wc) {
  const int per = 128 * 2048;
  int e = (blockIdx.x * blockDim.x + threadIdx.x) * 4;   // 196608 threads * 4 = 786432
  const float* src = (e < per) ? wq : (e < 2 * per) ? wk : wv;
  int off = e & (per - 1);
  float4 v = *(const float4*)(src + off);
  short4 r;
  r.x = f2bs(v.x); r.y = f2bs(v.y); r.z = f2bs(v.z); r.w = f2bs(v.w);
  *(short4*)(wc + e) = r;
}

// ---- Kernel 2: projection GEMM  C[8192][384] = X[8192][2048] @ Wc^T
// block = 2 waves (BM=32), grid = (256 Mtiles, 2 Nhalves of 192)
// wave: 16 rows x 12 N-tiles of 16. Direct global fragment loads (W is L1/L2-hot).
__global__ __launch_bounds__(128) void proj_kernel(const float* __restrict__ x,
                                                   const short* __restrict__ wc,
                                                   short* __restrict__ qb,
                                                   short* __restrict__ kb,
                                                   short* __restrict__ vt) {
  const int w = threadIdx.x >> 6;
  const int lane = threadIdx.x & 63;
  const int lo = lane & 15, g = lane >> 4;
  const int m0 = blockIdx.x * 32 + w * 16;
  const int n0 = blockIdx.y * 192;

  const float* xrow = x + (size_t)(m0 + lo) * DMODEL;

  floatx4 acc[12];
#pragma unroll
  for (int t = 0; t < 12; ++t) acc[t] = floatx4{0.f, 0.f, 0.f, 0.f};

  for (int k = 0; k < DMODEL; k += 32) {
    const float* xp = xrow + k + g * 8;
    float4 a0 = *(const float4*)(xp);
    float4 a1 = *(const float4*)(xp + 4);
    short8 af;
    af[0] = f2bs(a0.x); af[1] = f2bs(a0.y); af[2] = f2bs(a0.z); af[3] = f2bs(a0.w);
    af[4] = f2bs(a1.x); af[5] = f2bs(a1.y); af[6] = f2bs(a1.z); af[7] = f2bs(a1.w);
#pragma unroll
    for (int t = 0; t < 12; ++t) {
      short8 bf = *(const short8*)(wc + (size_t)(n0 + t * 16 + lo) * DMODEL + k + g * 8);
      acc[t] = __builtin_amdgcn_mfma_f32_16x16x32_bf16(af, bf, acc[t], 0, 0, 0);
    }
  }

#pragma unroll
  for (int t = 0; t < 12; ++t) {
    int n = n0 + t * 16 + lo;
#pragma unroll
    for (int j = 0; j < 4; ++j) {
      int m = m0 + g * 4 + j;                     // D layout: row=(lane>>4)*4+reg
      short bv = f2bs(acc[t][j]);
      if (n < HEADD) {
        qb[(size_t)m * HEADD + n] = bv;
      } else if (n < 2 * HEADD) {
        kb[(size_t)m * HEADD + (n - HEADD)] = bv;
      } else {
        int h = n - 2 * HEADD;
        int bb = m >> 12, s = m & (S_LEN - 1);
        vt[((size_t)bb * HEADD + h) * S_LEN + s] = bv;   // V transposed: [b][h][s]
      }
    }
  }
}

// ---- Kernel 3: dual flash attention + diff combine + RMSNorm
// 1 wave per block, 16 q rows; 512 blocks (b in {0,1} x 256 q-tiles)
__global__ __launch_bounds__(64) void attn_kernel(const short* __restrict__ qb,
                                                  const short* __restrict__ kb,
                                                  const short* __restrict__ vt,
                                                  const float* __restrict__ lq1,
                                                  const float* __restrict__ lq2,
                                                  const float* __restrict__ lk1,
                                                  const float* __restrict__ lk2,
                                                  const float* __restrict__ rmsw,
                                                  float* __restrict__ out) {
  const int lane = threadIdx.x;
  const int lo = lane & 15, g = lane >> 4;
  const int b = blockIdx.x >> 8;
  const int qt = blockIdx.x & 255;

  __shared__ short p_lds[2][16][40];   // row stride 40 shorts = 80B: conflict-free b128 reads

  // lambda scalar (cheap, per-lane redundant)
  float a1 = 0.f, a2 = 0.f;
  for (int i = 0; i < 64; ++i) {
    a1 = fmaf(lq1[i], lk1[i], a1);
    a2 = fmaf(lq2[i], lk2[i], a2);
  }
  const float lam = __expf(a1) - __expf(a2) + 0.7836057665316245f;

  // Q fragments (A operand: row = lane&15, k = (lane>>4)*8 + j)
  const short* qrow = qb + (size_t)(b * S_LEN + qt * 16 + lo) * HEADD;
  const short8 q1f0 = *(const short8*)(qrow + g * 8);
  const short8 q1f1 = *(const short8*)(qrow + 32 + g * 8);
  const short8 q2f0 = *(const short8*)(qrow + 64 + g * 8);
  const short8 q2f1 = *(const short8*)(qrow + 96 + g * 8);

  floatx4 acc1[8], acc2[8];
#pragma unroll
  for (int n = 0; n < 8; ++n) {
    acc1[n] = floatx4{0.f, 0.f, 0.f, 0.f};
    acc2[n] = floatx4{0.f, 0.f, 0.f, 0.f};
  }
  float m1[4], l1[4], m2[4], l2[4];
#pragma unroll
  for (int j = 0; j < 4; ++j) { m1[j] = -1e30f; l1[j] = 0.f; m2[j] = -1e30f; l2[j] = 0.f; }

  const short* kbase = kb + (size_t)b * S_LEN * HEADD;
  const short* vbase = vt + (size_t)b * HEADD * S_LEN;

  for (int kv = 0; kv < S_LEN; kv += 32) {
    floatx4 s1[2], s2[2];
#pragma unroll
    for (int t = 0; t < 2; ++t) {
      const short* krow = kbase + (size_t)(kv + t * 16 + lo) * HEADD;
      short8 k1f0 = *(const short8*)(krow + g * 8);
      short8 k1f1 = *(const short8*)(krow + 32 + g * 8);
      short8 k2f0 = *(const short8*)(krow + 64 + g * 8);
      short8 k2f1 = *(const short8*)(krow + 96 + g * 8);
      floatx4 z = floatx4{0.f, 0.f, 0.f, 0.f};
      floatx4 u1 = __builtin_amdgcn_mfma_f32_16x16x32_bf16(q1f0, k1f0, z, 0, 0, 0);
      s1[t] = __builtin_amdgcn_mfma_f32_16x16x32_bf16(q1f1, k1f1, u1, 0, 0, 0);
      floatx4 u2 = __builtin_amdgcn_mfma_f32_16x16x32_bf16(q2f0, k2f0, z, 0, 0, 0);
      s2[t] = __builtin_amdgcn_mfma_f32_16x16x32_bf16(q2f1, k2f1, u2, 0, 0, 0);
    }
#pragma unroll
    for (int t = 0; t < 2; ++t)
#pragma unroll
      for (int j = 0; j < 4; ++j) { s1[t][j] *= 0.125f; s2[t][j] *= 0.125f; }

    // per-row (D layout: row = g*4+j lives in 16-lane group) tile max
    float mt1[4], mt2[4];
#pragma unroll
    for (int j = 0; j < 4; ++j) {
      mt1[j] = fmaxf(s1[0][j], s1[1][j]);
      mt2[j] = fmaxf(s2[0][j], s2[1][j]);
    }
#pragma unroll
    for (int d = 1; d < 16; d <<= 1)
#pragma unroll
      for (int j = 0; j < 4; ++j) {
        mt1[j] = fmaxf(mt1[j], __shfl_xor(mt1[j], d));
        mt2[j] = fmaxf(mt2[j], __shfl_xor(mt2[j], d));
      }

    float f1[4], f2[4], rs1[4], rs2[4];
#pragma unroll
    for (int j = 0; j < 4; ++j) {
      float nm1 = fmaxf(m1[j], mt1[j]);
      f1[j] = __expf(m1[j] - nm1); m1[j] = nm1;
      float p10 = __expf(s1[0][j] - nm1);
      float p11 = __expf(s1[1][j] - nm1);
      s1[0][j] = p10; s1[1][j] = p11; rs1[j] = p10 + p11;
      float nm2 = fmaxf(m2[j], mt2[j]);
      f2[j] = __expf(m2[j] - nm2); m2[j] = nm2;
      float p20 = __expf(s2[0][j] - nm2);
      float p21 = __expf(s2[1][j] - nm2);
      s2[0][j] = p20; s2[1][j] = p21; rs2[j] = p20 + p21;
    }
#pragma unroll
    for (int d = 1; d < 16; d <<= 1)
#pragma unroll
      for (int j = 0; j < 4; ++j) {
        rs1[j] += __shfl_xor(rs1[j], d);
        rs2[j] += __shfl_xor(rs2[j], d);
      }
#pragma unroll
    for (int j = 0; j < 4; ++j) {
      l1[j] = l1[j] * f1[j] + rs1[j];
      l2[j] = l2[j] * f2[j] + rs2[j];
    }
#pragma unroll
    for (int n = 0; n < 8; ++n)
#pragma unroll
      for (int j = 0; j < 4; ++j) { acc1[n][j] *= f1[j]; acc2[n][j] *= f2[j]; }

    // transpose P (D layout) -> A layout via LDS, as bf16
#pragma unroll
    for (int t = 0; t < 2; ++t)
#pragma unroll
      for (int j = 0; j < 4; ++j) {
        p_lds[0][g * 4 + j][t * 16 + lo] = f2bs(s1[t][j]);
        p_lds[1][g * 4 + j][t * 16 + lo] = f2bs(s2[t][j]);
      }
    __syncthreads();
    short8 pa1 = *(const short8*)&p_lds[0][lo][g * 8];
    short8 pa2 = *(const short8*)&p_lds[1][lo][g * 8];

    // PV: B operand from transposed V (contiguous 16B per lane); V shared by both attns
#pragma unroll
    for (int n = 0; n < 8; ++n) {
      short8 vf = *(const short8*)(vbase + (size_t)(n * 16 + lo) * S_LEN + kv + g * 8);
      acc1[n] = __builtin_amdgcn_mfma_f32_16x16x32_bf16(pa1, vf, acc1[n], 0, 0, 0);
      acc2[n] = __builtin_amdgcn_mfma_f32_16x16x32_bf16(pa2, vf, acc2[n], 0, 0, 0);
    }
  }

  // epilogue: combine, RMS over 128 dims per row, scale, store
  float inv1[4], inv2[4];
#pragma unroll
  for (int j = 0; j < 4; ++j) { inv1[j] = 1.f / l1[j]; inv2[j] = 1.f / l2[j]; }
  float val[8][4];
  float ssq[4] = {0.f, 0.f, 0.f, 0.f};
#pragma unroll
  for (int n = 0; n < 8; ++n)
#pragma unroll
    for (int j = 0; j < 4; ++j) {
      float v = acc1[n][j] * inv1[j] - lam * (acc2[n][j] * inv2[j]);
      val[n][j] = v; ssq[j] += v * v;
    }
#pragma unroll
  for (int d = 1; d < 16; d <<= 1)
#pragma unroll
    for (int j = 0; j < 4; ++j) ssq[j] += __shfl_xor(ssq[j], d);
  float rr[4];
#pragma unroll
  for (int j = 0; j < 4; ++j)
    rr[j] = rsqrtf(ssq[j] * (1.f / 128.f) + 1.1920928955078125e-07f);
#pragma unroll
  for (int n = 0; n < 8; ++n) {
    float wgt = rmsw[n * 16 + lo];
#pragma unroll
    for (int j = 0; j < 4; ++j) {
      size_t row = (size_t)b * S_LEN + qt * 16 + g * 4 + j;
      out[row * HEADD + n * 16 + lo] = 0.21639423346837554f * val[n][j] * rr[j] * wgt;
    }
  }
}

extern "C" void kernel_launch(void* const* d_in, const int* in_sizes, int n_in,
                              void* d_out, int out_size, void* d_ws, size_t ws_size,
                              hipStream_t stream) {
  const float* x   = (const float*)d_in[0];
  const float* wq  = (const float*)d_in[1];
  const float* wk  = (const float*)d_in[2];
  const float* wv  = (const float*)d_in[3];
  const float* lq1 = (const float*)d_in[4];
  const float* lq2 = (const float*)d_in[5];
  const float* lk1 = (const float*)d_in[6];
  const float* lk2 = (const float*)d_in[7];
  const float* rw  = (const float*)d_in[8];
  float* out = (float*)d_out;

  char* ws = (char*)d_ws;
  short* qb = (short*)(ws);                    // 8192x128 bf16 = 2 MB
  short* kb = (short*)(ws + (2u << 20));       // 2 MB
  short* vt = (short*)(ws + (4u << 20));       // 2 MB  (V transposed [b][h][s])
  short* wc = (short*)(ws + (6u << 20));       // 384x2048 bf16 = 1.5 MB

  convw_kernel<<<768, 256, 0, stream>>>(wq, wk, wv, wc);
  proj_kernel<<<dim3(256, 2), 128, 0, stream>>>(x, wc, qb, kb, vt);
  attn_kernel<<<512, 64, 0, stream>>>(qb, kb, vt, lq1, lq2, lk1, lk2, rw, out);
}